// Round 13
// baseline (44.153 us; speedup 1.0000x reference)
//
#include <hip/hip_runtime.h>
#include <hip/hip_bf16.h>
#include <math.h>

// Problem constants (from reference): N=8 clouds, P=4096 points, D=3
constexpr int NB  = 8;
constexpr int PP  = 4096;

// Kernel A tiling
constexpr int TPB = 256;          // threads per block
constexpr int XPT = 4;            // x points per thread
constexpr int XCH = TPB * XPT;    // 1024 x points per block
constexpr int NXC = PP / XCH;     // 4 x chunks
constexpr int NYC = 32;           // contiguous y chunks
constexpr int YCH = PP / NYC;     // 128 y points per chunk
constexpr int GRIDA = 2 * NB * NXC * NYC;   // 2048 blocks (all resident at 8/CU)

// Kernel B segmentation (byte-identical to R5)
constexpr int NSEG = 16;              // segments per (dir, cloud)
constexpr int SEGP = PP / NSEG;       // 256 x points per segment
constexpr int NPART = 2 * NB * NSEG;  // 256 partials

// ---------------------------------------------------------------------------
// Kernel A (LDS-FREE): per (dir, cloud, x-chunk, y-chunk): partial min-d2
// over a CONTIGUOUS 128-point y-chunk for 1024 x points. The y access is
// block-uniform -> read y straight from global (compiler promotes the
// uniform address to scalar s_load via constant cache, or a single
// broadcast VMEM request) -> zero LDS-pipe traffic, no __syncthreads,
// no LDS alloc -> 8 blocks/CU all-resident (launch_bounds(256,8)).
// R12 post-mortem: the 15.8us A was LDS-pipe-saturated (~12 CU-cyc
// ds_read_b128 per j, shared by 4 SIMDs); unroll/waves couldn't fix a
// saturated shared pipe -> remove the pipe from the loop entirely.
// Math: m=-2x in regs; per j: yy=|y|^2 (3 VALU) then per k one 3-FMA
// chain + min. Per-chunk trip = clamp(yl - yc*128, 0, 128); empty ->
// write a+inf (masked later by B). ws layout identical to R5.
// ---------------------------------------------------------------------------
__global__ __launch_bounds__(TPB, 8) void nn_partial(
    const float* __restrict__ x, const float* __restrict__ y,
    const int* __restrict__ xlen, const int* __restrict__ ylen,
    float* __restrict__ ws)
{
    const int bid = (int)blockIdx.x;
    const int yc  = bid & (NYC - 1);
    const int xc  = (bid >> 5) & (NXC - 1);
    const int n   = (bid >> 7) & (NB - 1);
    const int dir = bid >> 10;

    const float* __restrict__ xs = dir ? y : x;    // query set
    const float* __restrict__ ys = dir ? x : y;    // search set
    const int yl = (dir ? xlen : ylen)[n];         // valid points in search set
    const int ql = (dir ? ylen : xlen)[n];         // valid points in query set

    // ---- load XPT x points, wave-contiguous: xi = wbase + k*64 + lane ----
    const int wave  = (int)threadIdx.x >> 6;
    const int lane  = (int)threadIdx.x & 63;
    const int wbase = xc * XCH + wave * (XPT * 64);   // 256 x points per wave

    float m0[XPT], m1[XPT], m2[XPT], a[XPT], emin[XPT];
    const float* __restrict__ xb = xs + (size_t)n * PP * 3;
#pragma unroll
    for (int k = 0; k < XPT; ++k) {
        const int xi = wbase + k * 64 + lane;
        float x0 = xb[xi * 3 + 0];
        float x1 = xb[xi * 3 + 1];
        float x2 = xb[xi * 3 + 2];
        m0[k] = -2.f * x0; m1[k] = -2.f * x1; m2[k] = -2.f * x2;
        a[k]  = fmaf(x0, x0, fmaf(x1, x1, x2 * x2));
        emin[k] = INFINITY;
    }

    // trip count for this contiguous chunk
    int jend = yl - yc * YCH;
    if (jend > YCH) jend = YCH;            // may be <= 0 (empty chunk)

    // whole-wave skip when every query row this wave owns is padding
    if (ql > wbase && jend > 0) {
        // block-uniform y reads -> scalar loads through constant cache
        const float* __restrict__ yp = ys + ((size_t)n * PP + (size_t)yc * YCH) * 3;
#pragma unroll 4
        for (int j = 0; j < jend; ++j) {
            const float y0 = yp[j * 3 + 0];
            const float y1 = yp[j * 3 + 1];
            const float y2 = yp[j * 3 + 2];
            const float yy = fmaf(y0, y0, fmaf(y1, y1, y2 * y2));
#pragma unroll
            for (int k = 0; k < XPT; ++k) {
                float e = fmaf(m0[k], y0, fmaf(m1[k], y1, fmaf(m2[k], y2, yy)));
                emin[k] = fminf(emin[k], e);
            }
        }
    }

    float* __restrict__ w = ws + ((size_t)(dir * NB + n) * NYC + yc) * PP;
#pragma unroll
    for (int k = 0; k < XPT; ++k) {
        w[wbase + k * 64 + lane] = a[k] + emin[k];   // inf for skipped/empty
    }
}

// ---------------------------------------------------------------------------
// Kernel B (byte-identical to R5): per (dir, cloud, segment): min over the
// 32 chunks, mask padded x, sum, divide by max(len,1)*NB, write partial.
// ---------------------------------------------------------------------------
__global__ __launch_bounds__(256) void reduce_cloud(
    const float* __restrict__ ws,
    const int* __restrict__ xlen, const int* __restrict__ ylen,
    float* __restrict__ partial)
{
    const int b   = blockIdx.x;          // 0..255
    const int seg = b & (NSEG - 1);
    const int c   = b >> 4;              // 0..15
    const int dir = c >> 3;
    const int n   = c & (NB - 1);
    const int xl  = (dir ? ylen : xlen)[n];   // valid query points

    const float* __restrict__ w = ws + (size_t)c * NYC * PP;
    const int i = seg * SEGP + (int)threadIdx.x;

    float m = w[i];
#pragma unroll
    for (int ch = 1; ch < NYC; ++ch) m = fminf(m, w[(size_t)ch * PP + i]);
    float sum = (i < xl) ? m : 0.f;

    // block reduction (4 waves of 64)
#pragma unroll
    for (int off = 32; off > 0; off >>= 1) sum += __shfl_xor(sum, off);
    __shared__ float ls[4];
    const int lane = (int)threadIdx.x & 63;
    const int wv   = (int)threadIdx.x >> 6;
    if (lane == 0) ls[wv] = sum;
    __syncthreads();
    if (threadIdx.x == 0) {
        float tot = ls[0] + ls[1] + ls[2] + ls[3];
        int d = xl > 1 ? xl : 1;
        partial[b] = tot / (float)d / (float)NB;
    }
}

// ---------------------------------------------------------------------------
// Kernel C (identical to R5): sum the 256 partials -> scalar output.
// ---------------------------------------------------------------------------
__global__ __launch_bounds__(256) void final_sum(
    const float* __restrict__ partial, float* __restrict__ out)
{
    float v = partial[threadIdx.x];
#pragma unroll
    for (int off = 32; off > 0; off >>= 1) v += __shfl_xor(v, off);
    __shared__ float ls[4];
    const int lane = (int)threadIdx.x & 63;
    const int wv   = (int)threadIdx.x >> 6;
    if (lane == 0) ls[wv] = v;
    __syncthreads();
    if (threadIdx.x == 0) out[0] = ls[0] + ls[1] + ls[2] + ls[3];
}

// ---------------------------------------------------------------------------
// Fallback (ws too small): LDS-free uniform-y loop, multi-pass over chunks;
// block sum + atomicAdd of the pre-divided contribution. d_out zeroed first.
// ---------------------------------------------------------------------------
__global__ __launch_bounds__(TPB) void chamfer_atomic(
    const float* __restrict__ x, const float* __restrict__ y,
    const int* __restrict__ xlen, const int* __restrict__ ylen,
    float* __restrict__ out)
{
    int bid = blockIdx.x;
    const int xc  = bid & (NXC - 1);
    const int n   = (bid >> 2) & (NB - 1);
    const int dir = bid >> 5;

    const float* __restrict__ xs = dir ? y : x;
    const float* __restrict__ ys = dir ? x : y;
    const int yl = (dir ? xlen : ylen)[n];
    const int xl = (dir ? ylen : xlen)[n];

    float m0[XPT], m1[XPT], m2[XPT], a[XPT], emin[XPT];
    const int wave  = (int)threadIdx.x >> 6;
    const int lane  = (int)threadIdx.x & 63;
    const int wbase = xc * XCH + wave * (XPT * 64);
    const float* __restrict__ xb = xs + (size_t)n * PP * 3;
#pragma unroll
    for (int k = 0; k < XPT; ++k) {
        const int xi = wbase + k * 64 + lane;
        float x0 = xb[xi * 3 + 0];
        float x1 = xb[xi * 3 + 1];
        float x2 = xb[xi * 3 + 2];
        m0[k] = -2.f * x0; m1[k] = -2.f * x1; m2[k] = -2.f * x2;
        a[k]  = fmaf(x0, x0, fmaf(x1, x1, x2 * x2));
        emin[k] = INFINITY;
    }

    const float* __restrict__ yp = ys + (size_t)n * PP * 3;
#pragma unroll 4
    for (int j = 0; j < yl; ++j) {
        const float y0 = yp[j * 3 + 0];
        const float y1 = yp[j * 3 + 1];
        const float y2 = yp[j * 3 + 2];
        const float yy = fmaf(y0, y0, fmaf(y1, y1, y2 * y2));
#pragma unroll
        for (int k = 0; k < XPT; ++k) {
            float e = fmaf(m0[k], y0, fmaf(m1[k], y1, fmaf(m2[k], y2, yy)));
            emin[k] = fminf(emin[k], e);
        }
    }

    float sum = 0.f;
#pragma unroll
    for (int k = 0; k < XPT; ++k) {
        const int xi = wbase + k * 64 + lane;
        if (xi < xl) sum += a[k] + emin[k];
    }
#pragma unroll
    for (int off = 32; off > 0; off >>= 1) sum += __shfl_xor(sum, off);
    __shared__ float ls[4];
    if (lane == 0) ls[wave] = sum;
    __syncthreads();
    if (threadIdx.x == 0) {
        float tot = ls[0] + ls[1] + ls[2] + ls[3];
        int d = xl > 1 ? xl : 1;
        atomicAdd(out, tot / (float)d / (float)NB);
    }
}

extern "C" void kernel_launch(void* const* d_in, const int* in_sizes, int n_in,
                              void* d_out, int out_size, void* d_ws, size_t ws_size,
                              hipStream_t stream) {
    const float* x  = (const float*)d_in[0];
    const float* y  = (const float*)d_in[1];
    const int* xl   = (const int*)d_in[2];
    const int* yl   = (const int*)d_in[3];
    float* out      = (float*)d_out;

    const size_t ws_floats = (size_t)2 * NB * NYC * PP;             // partial d2 table
    const size_t ws_need   = (ws_floats + NPART) * sizeof(float);   // + partials

    if (ws_size >= ws_need) {
        float* ws      = (float*)d_ws;
        float* partial = ws + ws_floats;
        nn_partial<<<GRIDA, TPB, 0, stream>>>(x, y, xl, yl, ws);
        reduce_cloud<<<NPART, 256, 0, stream>>>(ws, xl, yl, partial);
        final_sum<<<1, 256, 0, stream>>>(partial, out);
    } else {
        hipMemsetAsync(d_out, 0, sizeof(float), stream);
        const int gridF = 2 * NB * NXC;         // 64 blocks
        chamfer_atomic<<<gridF, TPB, 0, stream>>>(x, y, xl, yl, out);
    }
}